// Round 6
// baseline (452.442 us; speedup 1.0000x reference)
//
#include <hip/hip_runtime.h>
#include <math.h>

#define B_ 8
#define Q_ 100
#define T_ 50
#define HW_ 65536
#define NSEG 128
#define SEG (HW_ / NSEG)    // 512 K per block
#define NCH (SEG / 32)      // 16 chunks of K=32
#define NW 8                // waves per block
#define NSTR 52             // N stride in ws (50 t + sum col + pad)

// workspace layout (floats)
#define DSZ (B_ * Q_ * NSTR)       // 41600
#define WS_D1 0
#define WS_D2 DSZ
#define WS_SLG (2 * DSZ)           // 800: sum log2(sigma) per (b,q)
#define WS_ST (2 * DSZ + B_ * Q_)  // 400: sum t per (b,t)
#define WS_TOTAL (2 * DSZ + B_ * Q_ + B_ * T_)

#define LOG2E 1.44269504089f
#define LN2 0.69314718056f

typedef __attribute__((ext_vector_type(8))) short bf16x8;
typedef __attribute__((ext_vector_type(4))) float f32x4;
typedef __attribute__((ext_vector_type(4))) unsigned u32x4;
union BFU { u32x4 u; bf16x8 h; };

__device__ __forceinline__ unsigned pack2bf(float a, float b) {
    unsigned ua = __float_as_uint(a), ub = __float_as_uint(b);
    ua = ua + 0x7fffu + ((ua >> 16) & 1u);
    ub = ub + 0x7fffu + ((ub >> 16) & 1u);
    return (ua >> 16) | (ub & 0xffff0000u);
}

__global__ void zero_ws(float* ws) {
    int i = blockIdx.x * blockDim.x + threadIdx.x;
    if (i < WS_TOTAL) ws[i] = 0.f;
}

// 512-thread block = 8 waves; wave w owns M-tile w (rows 16w..16w+15).
// t staged ONCE per block as an LDS bitmask (ballot); K-loop is barrier-free.
// acc = 8 tiles = 32 AGPR/wave -> ~4 waves/SIMD occupancy.
__global__ __launch_bounds__(512, 3) void gemm_fused(const float* __restrict__ pred,
                                                     const int* __restrict__ tgt,
                                                     float* __restrict__ ws) {
    const int seg = blockIdx.x;
    const int b   = blockIdx.y;
    const int tid = threadIdx.x;
    const int wave = tid >> 6;
    const int lane = tid & 63;
    const int quad = lane >> 4;
    const int l16  = lane & 15;

    __shared__ unsigned tb[64][17];   // bitmask: 50 rows x 512 bits; odd stride

    // ---- x pointer (row clamped; clamped rows never stored) ----
    const int m = wave * 16 + l16;
    const int mr = m < Q_ ? m : Q_ - 1;
    const float* xp = pred + ((size_t)b * Q_ + mr) * HW_ + (size_t)seg * SEG + quad * 8;

    // prefetch chunk 0 of x before staging (independent of LDS)
    float4 x00 = *(const float4*)(xp);
    float4 x01 = *(const float4*)(xp + 4);

    // ---- stage t bitmask via ballot; popcount -> Sigma t ----
    const int* tbase = tgt + (size_t)b * T_ * HW_ + (size_t)seg * SEG;
    for (int r = wave; r < T_; r += NW) {
        float c = 0.f;
#pragma unroll
        for (int wi = 0; wi < SEG / 64; ++wi) {
            int v = tbase[(size_t)r * HW_ + wi * 64 + lane];
            unsigned long long mask = __ballot(v != 0);
            if (lane == 0) {
                tb[r][wi * 2]     = (unsigned)mask;
                tb[r][wi * 2 + 1] = (unsigned)(mask >> 32);
                c += (float)__popcll(mask);
            }
        }
        if (lane == 0) atomicAdd(&ws[WS_ST + b * T_ + r], c);
    }
    __syncthreads();

    f32x4 accx[4], accs[4];
#pragma unroll
    for (int nt = 0; nt < 4; ++nt) { accx[nt] = (f32x4)(0.f); accs[nt] = (f32x4)(0.f); }
    float slg = 0.f;   // sum log2(sigma)

    float4 xb[2][2];
    unsigned twb[2][4];

    auto load = [&](int ch, int pb) {
        xb[pb][0] = *(const float4*)(xp + ch * 32);
        xb[pb][1] = *(const float4*)(xp + ch * 32 + 4);
#pragma unroll
        for (int nt = 0; nt < 4; ++nt)
            twb[pb][nt] = tb[nt * 16 + l16][ch];
    };

    auto compute = [&](int pb) {
        // x -> bf16 + sigma(bf16) + running log2-sigma sum
        BFU xf, sf;
#pragma unroll
        for (int h = 0; h < 2; ++h)
#pragma unroll
            for (int e = 0; e < 4; e += 2) {
                float v0 = (&xb[pb][h].x)[e];
                float v1 = (&xb[pb][h].x)[e + 1];
                float e0 = __builtin_amdgcn_exp2f(-LOG2E * v0);
                float e1 = __builtin_amdgcn_exp2f(-LOG2E * v1);
                float d0 = 1.f + e0, d1 = 1.f + e1;
                float s0 = __builtin_amdgcn_rcpf(d0);
                float s1 = __builtin_amdgcn_rcpf(d1);
                slg -= __builtin_amdgcn_logf(d0);   // log2(sigma) = -log2(1+e)
                slg -= __builtin_amdgcn_logf(d1);
                xf.u[h * 2 + e / 2] = pack2bf(v0, v1);
                sf.u[h * 2 + e / 2] = pack2bf(s0, s1);
            }
        // t bitmask -> bf16 {0,1} fragments; col n==50 forced to ones
        BFU tf[4];
#pragma unroll
        for (int nt = 0; nt < 4; ++nt) {
            unsigned tw = twb[pb][nt];
            if (nt == 3) tw = (l16 == 2) ? 0xffffffffu : tw;
            unsigned byte = (tw >> (quad * 8)) & 0xffu;
#pragma unroll
            for (int j = 0; j < 4; ++j) {
                unsigned b0 = (byte >> (2 * j)) & 1u;
                unsigned b1 = (byte >> (2 * j + 1)) & 1u;
                tf[nt].u[j] = b0 * 0x3F80u + b1 * 0x3F800000u;
            }
        }
#pragma unroll
        for (int nt = 0; nt < 4; ++nt) {
            accx[nt] = __builtin_amdgcn_mfma_f32_16x16x32_bf16(xf.h, tf[nt].h, accx[nt], 0, 0, 0);
            accs[nt] = __builtin_amdgcn_mfma_f32_16x16x32_bf16(sf.h, tf[nt].h, accs[nt], 0, 0, 0);
        }
    };

    // chunk 0 x already in flight
    xb[0][0] = x00; xb[0][1] = x01;
#pragma unroll
    for (int nt = 0; nt < 4; ++nt) twb[0][nt] = tb[nt * 16 + l16][0];

#pragma unroll 2
    for (int ch = 0; ch < NCH; ++ch) {
        const int pb = ch & 1;
        if (ch + 1 < NCH) load(ch + 1, pb ^ 1);
        compute(pb);
    }

    // ---- epilogue ----
    // Sigma log2(sigma) per q-row: reduce across quads
    {
        float v = slg;
        v += __shfl_xor(v, 16);
        v += __shfl_xor(v, 32);
        if (quad == 0 && m < Q_) atomicAdd(&ws[WS_SLG + b * Q_ + m], v);
    }
    // D atomics; C/D layout: col = l16 (within nt tile), row = quad*4 + r
#pragma unroll
    for (int nt = 0; nt < 4; ++nt) {
        int n = nt * 16 + l16;
        if (n > T_) continue;
#pragma unroll
        for (int r = 0; r < 4; ++r) {
            int mm = wave * 16 + quad * 4 + r;
            if (mm < Q_) {
                size_t idx = ((size_t)b * Q_ + mm) * NSTR + n;
                atomicAdd(&ws[WS_D1 + idx], accx[nt][r]);
                atomicAdd(&ws[WS_D2 + idx], accs[nt][r]);
            }
        }
    }
}

__global__ void finalize(const float* __restrict__ ws, float* __restrict__ out) {
    int i = blockIdx.x * blockDim.x + threadIdx.x;
    if (i >= B_ * Q_ * T_) return;
    int b = i / (Q_ * T_);
    int r = i % (Q_ * T_);
    int q = r / T_;
    int t = r % T_;
    float dx   = ws[WS_D1 + ((size_t)b * Q_ + q) * NSTR + t];
    float ds   = ws[WS_D2 + ((size_t)b * Q_ + q) * NSTR + t];
    float sumx = ws[WS_D1 + ((size_t)b * Q_ + q) * NSTR + T_];  // Sigma x (ones col)
    float ssum = ws[WS_D2 + ((size_t)b * Q_ + q) * NSTR + T_];  // Sigma sigmoid
    float slg  = ws[WS_SLG + b * Q_ + q];                       // Sigma log2 sigma
    float st   = ws[WS_ST + b * T_ + t];                        // Sigma t
    float sneg = sumx - LN2 * slg;                              // Sigma softplus(x)
    float ce = (sneg - dx) * (1.f / (float)HW_);
    float dice = 1.f - (2.f * ds + 1.f) / (ssum + st + 1.f);
    out[i] = ce + dice;
}

extern "C" void kernel_launch(void* const* d_in, const int* in_sizes, int n_in,
                              void* d_out, int out_size, void* d_ws, size_t ws_size,
                              hipStream_t stream) {
    const float* pred = (const float*)d_in[0];
    const int* tgt = (const int*)d_in[1];
    float* ws = (float*)d_ws;
    float* out = (float*)d_out;

    zero_ws<<<(WS_TOTAL + 255) / 256, 256, 0, stream>>>(ws);
    dim3 g(NSEG, B_, 1);
    gemm_fused<<<g, 512, 0, stream>>>(pred, tgt, ws);
    finalize<<<(B_ * Q_ * T_ + 255) / 256, 256, 0, stream>>>(ws, out);
}